// Round 9
// baseline (89.057 us; speedup 1.0000x reference)
//
#include <hip/hip_runtime.h>

#define NB_BS   2048
#define NB_NINP 512
#define NB_NHID 512
#define NB_K    16
#define NB_T    8
#define NB_M    32
#define NB_C    768   // T * 3 * M
#define H_OUT_ELEMS (NB_BS * NB_NHID)   // 1048576

// ---------------------------------------------------------------------------
// Kernel 1: gi'[b][c] = sum_i x[b][i]*Wih[c][i] + bih[c] + (gate<2 ? bhh[c] : 0)
// 32x64 tile, BK=64, 256 threads, 2x4 micro-tile, DOUBLE-BUFFERED LDS
// (52 KB -> 3 blocks/CU = 3 waves/SIMD, ONE barrier per slab -- r8's 16-wave
// single-buffer version drained the whole CU at 16 barriers in lockstep).
// Grid (64,12) = 768 = 3/CU balanced. B-tile XOR-swizzled per row quad so the
// global load stays k-fast coalesced, LDS writes are 2-way, and the b128
// compute reads are a conflict-free permutation. A-tile pad 34: b64 row reads
// hit 16 unique 2-bank slots covering all banks (broadcast for dup lanes).
// ---------------------------------------------------------------------------
__global__ __launch_bounds__(256, 3)
void k1_gemm_gi(const float* __restrict__ x, const float* __restrict__ Wih,
                const float* __restrict__ bih, const float* __restrict__ bhh,
                float* __restrict__ gi)
{
    __shared__ __align__(16) float As[2][64][34];   // 17.4 KB
    __shared__ __align__(16) float Bs[2][64][68];   // 34.8 KB

    const int tid  = threadIdx.x;
    const int row0 = blockIdx.x * 32;     // 64 row blocks
    const int col0 = blockIdx.y * 64;     // 12 col blocks
    const int rg   = tid & 15;            // rows rg*2, rg*2+1
    const int cg   = tid >> 4;            // cols cg*4..+3 (4 cg per wave)

    // staging: every thread owns k-quad akq = (tid&15)*4 (k-fast => coalesced)
    const int akq  = (tid & 15) * 4;
    const int ar0  = tid >> 4, ar1 = ar0 + 16;          // A rows
    const int swz  = (tid & 7) * 4;                     // B LDS col swizzle

    const float* xb = x   + (size_t)row0 * NB_NINP + akq;
    const float* wb = Wih + (size_t)col0 * NB_NINP + akq;

    float4 a0 = *(const float4*)&xb[(size_t)ar0 * NB_NINP];
    float4 a1 = *(const float4*)&xb[(size_t)ar1 * NB_NINP];
    float4 bf[4];
    #pragma unroll
    for (int L = 0; L < 4; ++L)
        bf[L] = *(const float4*)&wb[(size_t)(L * 16 + (tid >> 4)) * NB_NINP];

    float acc[2][4];
    #pragma unroll
    for (int i = 0; i < 2; ++i)
        #pragma unroll
        for (int e = 0; e < 4; ++e) acc[i][e] = 0.f;

    // prologue: stage slab 0 into buf 0
    {
        const float av0[4] = {a0.x, a0.y, a0.z, a0.w};
        const float av1[4] = {a1.x, a1.y, a1.z, a1.w};
        #pragma unroll
        for (int j = 0; j < 4; ++j) {
            As[0][akq + j][ar0] = av0[j];
            As[0][akq + j][ar1] = av1[j];
        }
        #pragma unroll
        for (int L = 0; L < 4; ++L) {
            const float bv[4] = {bf[L].x, bf[L].y, bf[L].z, bf[L].w};
            const int bcol = (L * 16 + (tid >> 4)) ^ swz;
            #pragma unroll
            for (int j = 0; j < 4; ++j) Bs[0][akq + j][bcol] = bv[j];
        }
    }
    __syncthreads();

    for (int s = 0; s < 8; ++s) {         // 8 slabs of BK=64
        const int buf = s & 1;
        if (s < 7) {                       // issue next-slab loads EARLY
            const int kb = (s + 1) * 64;
            a0 = *(const float4*)&xb[(size_t)ar0 * NB_NINP + kb];
            a1 = *(const float4*)&xb[(size_t)ar1 * NB_NINP + kb];
            #pragma unroll
            for (int L = 0; L < 4; ++L)
                bf[L] = *(const float4*)&wb[(size_t)(L * 16 + (tid >> 4)) * NB_NINP + kb];
        }
        #pragma unroll 16
        for (int kk = 0; kk < 64; ++kk) {
            const int sB = ((kk >> 2) & 7) * 4;
            const float2 av = *(const float2*)&As[buf][kk][rg * 2];
            const float4 wv = *(const float4*)&Bs[buf][kk][(cg * 4) ^ sB];
            const float avv[2] = {av.x, av.y};
            const float wvv[4] = {wv.x, wv.y, wv.z, wv.w};
            #pragma unroll
            for (int i = 0; i < 2; ++i)
                #pragma unroll
                for (int e = 0; e < 4; ++e)
                    acc[i][e] = fmaf(avv[i], wvv[e], acc[i][e]);
        }
        if (s < 7) {                       // write next slab LATE (other buf)
            const int nb = buf ^ 1;
            const float av0[4] = {a0.x, a0.y, a0.z, a0.w};
            const float av1[4] = {a1.x, a1.y, a1.z, a1.w};
            #pragma unroll
            for (int j = 0; j < 4; ++j) {
                As[nb][akq + j][ar0] = av0[j];
                As[nb][akq + j][ar1] = av1[j];
            }
            #pragma unroll
            for (int L = 0; L < 4; ++L) {
                const float bv[4] = {bf[L].x, bf[L].y, bf[L].z, bf[L].w};
                const int bcol = (L * 16 + (tid >> 4)) ^ swz;
                #pragma unroll
                for (int j = 0; j < 4; ++j) Bs[nb][akq + j][bcol] = bv[j];
            }
        }
        __syncthreads();                   // one barrier per slab
    }

    float bias[4];
    #pragma unroll
    for (int e = 0; e < 4; ++e) {
        const int c = col0 + cg * 4 + e;
        bias[e] = bih[c] + ((c % 96) < 64 ? bhh[c] : 0.f);
    }
    #pragma unroll
    for (int i = 0; i < 2; ++i) {
        float4 o;
        o.x = acc[i][0] + bias[0]; o.y = acc[i][1] + bias[1];
        o.z = acc[i][2] + bias[2]; o.w = acc[i][3] + bias[3];
        *(float4*)&gi[(size_t)(row0 + rg * 2 + i) * NB_C + col0 + cg * 4] = o;
    }
}

// ---------------------------------------------------------------------------
// Kernel 2: fused gh-GEMM + GRU + write-key logits + gumbel-argmax + gather.
// r8 structure (proven 53.9us / 60 VGPR / no spill): 256 blocks x 1024 thr
// (16 waves = 4 waves/SIMD), waves_per_eu(4,4) spill guard, wave (bl,kh),
// 2 passes of 4 k's, acc[4][12], P planes XOR-swizzled.
// NEW epilogue: packed multi-value butterfly -- the 4 p-sums merge into lane
// bits 4/3 during the m-reduction (9 shfl vs 20), finished logits go to a
// wave-local LG row (1 predicated ds_write), and the argmax reads them back
// as 2 broadcast b128 (same-wave DS ordering, no barrier). DS/k: 24 -> 12.
// ---------------------------------------------------------------------------
__global__ __launch_bounds__(1024)
__attribute__((amdgpu_waves_per_eu(4, 4)))
void k2_fused(const float* __restrict__ h,      const float* __restrict__ Whh,
              const float* __restrict__ bhh,    const float* __restrict__ wread,
              const float* __restrict__ wwrite, const float* __restrict__ gumb,
              const float* __restrict__ gi,     float* __restrict__ out)
{
    __shared__ __align__(16) float4 P[3][32][64];   // 98304 B  W_hh planes
    __shared__ __align__(16) float4 WWT4[16][64];   // 16384 B  [f][half*32+m]:p-quad
    __shared__ __align__(16) float WR[512];         //  2048 B  w_read [m][f]
    __shared__ __align__(16) float HT[8][32][20];   // 20480 B  [bl][m][k]
    __shared__ __align__(16) float HR2T[8][16][20]; // 10240 B  [bl][f][k]
    __shared__ __align__(16) float LG[8][16][8];    //  4096 B  [bl][k][t]

    const int tid  = threadIdx.x;
    const int wave = tid >> 6, lane = tid & 63;
    const int bl   = wave >> 1, kh = wave & 1;
    const int b    = blockIdx.x * 8 + bl;
    const int m_   = lane & 31, half = lane >> 5;

    // ---- stage W_hh planes (value for reading-lane sl at contraction mm
    //      lands at float4 slot sl ^ (mm&7) of row [j>>2][mm])
    float* PF = (float*)P;
    for (int i = tid; i < 24576; i += 1024) {       // Whh flat [c][m]; c=t*96+gc*32+mout
        const int c = i >> 5, mm = i & 31;
        const int t = c / 96, rem = c - t * 96;
        const int gc = rem >> 5, mout = rem & 31;
        const int j  = (t >> 1) * 3 + gc;
        const int sl = ((t & 1) * 32 + mout) ^ (mm & 7);
        PF[(((j >> 2) * 32 + mm) * 64 + sl) * 4 + (j & 3)] = Whh[i];
    }
    for (int i = tid; i < 4096; i += 1024) {        // wwrite flat [t][m][f]
        const int t = i >> 9, mo = (i >> 4) & 31, f = i & 15;
        ((float*)WWT4)[(f * 64 + (t & 1) * 32 + mo) * 4 + (t >> 1)] = wwrite[i];
    }
    if (tid < 512) WR[tid] = wread[tid];
    #pragma unroll
    for (int e = 0; e < 4; ++e) {                   // this wave's h half-row, transposed
        const int idx = kh * 256 + e * 64 + lane;
        HT[bl][idx & 31][idx >> 5] = h[(size_t)b * NB_NHID + idx];
    }
    __syncthreads();   // only barrier; everything below is wave-local

    // ---- h_read for this wave's 8 k's: lane owns (k = kh*8 + lane>>3, f-pair)
    {
        const int kq = kh * 8 + (lane >> 3);
        const int f0 = (lane & 7) * 2;
        float s0 = 0.f, s1 = 0.f;
        #pragma unroll 8
        for (int mm = 0; mm < 32; ++mm) {
            const float hv = HT[bl][mm][kq];
            s0 = fmaf(hv, WR[mm * 16 + f0], s0);
            s1 = fmaf(hv, WR[mm * 16 + f0 + 1], s1);
        }
        HR2T[bl][f0    ][kq] = s0;
        HR2T[bl][f0 + 1][kq] = s1;
    }

    // ---- per-lane gi' (bih+bhh_{r,z} folded by k1) and bhh_n
    float gi_r[4][3], bhn[4];
    #pragma unroll
    for (int p = 0; p < 4; ++p) {
        const int t = 2 * p + half;
        #pragma unroll
        for (int gc = 0; gc < 3; ++gc)
            gi_r[p][gc] = gi[(size_t)b * NB_C + t * 96 + gc * 32 + m_];
        bhn[p] = bhh[t * 96 + 64 + m_];
    }

    #pragma unroll 1
    for (int pass = 0; pass < 2; ++pass) {
        const int k0 = kh * 8 + pass * 4;

        // ---- gh GEMM, 4 k's: 48 FMA per mm; 3 spread b128 + 1 broadcast b128
        float acc[4][12];
        #pragma unroll
        for (int r = 0; r < 4; ++r)
            #pragma unroll
            for (int j = 0; j < 12; ++j) acc[r][j] = 0.f;

        #pragma unroll 4
        for (int mm = 0; mm < 32; ++mm) {
            const int sw = lane ^ (mm & 7);          // undo staging swizzle
            const float4 w0 = P[0][mm][sw];
            const float4 w1 = P[1][mm][sw];
            const float4 w2 = P[2][mm][sw];
            const float4 hv = *(const float4*)&HT[bl][mm][k0];   // broadcast
            const float wj[12] = {w0.x,w0.y,w0.z,w0.w, w1.x,w1.y,w1.z,w1.w,
                                  w2.x,w2.y,w2.z,w2.w};
            const float hr4[4] = {hv.x, hv.y, hv.z, hv.w};
            #pragma unroll
            for (int r = 0; r < 4; ++r)
                #pragma unroll
                for (int j = 0; j < 12; ++j)
                    acc[r][j] = fmaf(hr4[r], wj[j], acc[r][j]);
        }

        // ---- write-key dot ww[r][p] = sum_f w_write[t][m_][f] * h_read[k][f]
        float ww[4][4];
        #pragma unroll
        for (int r = 0; r < 4; ++r)
            #pragma unroll
            for (int p = 0; p < 4; ++p) ww[r][p] = 0.f;
        #pragma unroll 4
        for (int f = 0; f < 16; ++f) {
            const float4 wt4 = WWT4[f][half * 32 + m_];           // b128 spread
            const float4 hka = *(const float4*)&HR2T[bl][f][k0];  // broadcast
            const float wt[4] = {wt4.x, wt4.y, wt4.z, wt4.w};
            const float hk[4] = {hka.x, hka.y, hka.z, hka.w};
            #pragma unroll
            for (int r = 0; r < 4; ++r)
                #pragma unroll
                for (int p = 0; p < 4; ++p)
                    ww[r][p] = fmaf(hk[r], wt[p], ww[r][p]);
        }

        // ---- per-k epilogue: gates, packed logit reduce, argmax, gather
        #pragma unroll
        for (int r = 0; r < 4; ++r) {
            const int k = k0 + r;
            const float h2v = HT[bl][m_][k];
            float hn[4], part[4];
            #pragma unroll
            for (int p = 0; p < 4; ++p) {
                const float xr = gi_r[p][0] + acc[r][p*3+0];
                const float xz = gi_r[p][1] + acc[r][p*3+1];
                const float gn = bhn[p]     + acc[r][p*3+2];
                const float rg = 1.f / (1.f + __expf(-xr));
                const float zg = 1.f / (1.f + __expf(-xz));
                const float xn = gi_r[p][2] + rg * gn;
                const float e2 = __expf(2.f * xn);
                const float tn = 1.f - 2.f / (e2 + 1.f);   // tanh
                const float hv2 = (1.f - zg) * tn + zg * h2v;
                hn[p] = hv2;
                part[p] = hv2 * ww[r][p];                  // logit partial
            }
            // packed butterfly over m: p-low -> lane bit4, p-high -> lane bit3
            #pragma unroll
            for (int p = 0; p < 4; ++p)
                part[p] += __shfl_xor(part[p], 16, 64);
            const bool b4 = (lane & 16) != 0, b3 = (lane & 8) != 0;
            float v01 = b4 ? part[1] : part[0];
            float v23 = b4 ? part[3] : part[2];
            v01 += __shfl_xor(v01, 8, 64);
            v23 += __shfl_xor(v23, 8, 64);
            float v = b3 ? v23 : v01;
            v += __shfl_xor(v, 4, 64);
            v += __shfl_xor(v, 2, 64);
            v += __shfl_xor(v, 1, 64);
            if ((lane & 7) == 0) {       // 8 lanes: one per (p,half) = t
                const int p_ = ((lane >> 4) & 1) | (((lane >> 3) & 1) << 1);
                LG[bl][k][2 * p_ + half] = v;
            }
            // same-wave DS ordering: LG[k][0..7] complete for this wave's k
            const float4 l0 = *(const float4*)&LG[bl][k][0];   // broadcast
            const float4 l1 = *(const float4*)&LG[bl][k][4];
            const float* gp = gumb + ((size_t)b * NB_K + k) * NB_T;
            const float4 ga = *(const float4*)gp;
            const float4 gb = *(const float4*)(gp + 4);
            const float s[8] = {l0.x+ga.x, l0.y+ga.y, l0.z+ga.z, l0.w+ga.w,
                                l1.x+gb.x, l1.y+gb.y, l1.z+gb.z, l1.w+gb.w};
            float best = s[0]; int bt = 0;
            #pragma unroll
            for (int t2 = 1; t2 < 8; ++t2)
                if (s[t2] > best) { best = s[t2]; bt = t2; }   // first-max
            const int pstar = bt >> 1, hstar = bt & 1;
            float hsel = hn[0];
            hsel = (pstar == 1) ? hn[1] : hsel;
            hsel = (pstar == 2) ? hn[2] : hsel;
            hsel = (pstar == 3) ? hn[3] : hsel;
            if (half == hstar)
                out[(size_t)b * NB_NHID + k * 32 + m_] = hsel;
            if (lane < 8)
                out[H_OUT_ELEMS + ((size_t)b * NB_K + k) * NB_T + lane] =
                    (lane == bt) ? 1.f : 0.f;
        }
    }
}

extern "C" void kernel_launch(void* const* d_in, const int* in_sizes, int n_in,
                              void* d_out, int out_size, void* d_ws, size_t ws_size,
                              hipStream_t stream) {
    const float* x      = (const float*)d_in[0];
    const float* h      = (const float*)d_in[1];
    const float* Wih    = (const float*)d_in[2];
    const float* Whh    = (const float*)d_in[3];
    const float* bih    = (const float*)d_in[4];
    const float* bhh    = (const float*)d_in[5];
    const float* wread  = (const float*)d_in[6];
    const float* wwrite = (const float*)d_in[7];
    const float* gumb   = (const float*)d_in[8];
    float* out = (float*)d_out;
    float* gi  = (float*)d_ws;   // 2048*768*4 = 6 MB scratch

    k1_gemm_gi<<<dim3(64, 12), 256, 0, stream>>>(x, Wih, bih, bhh, gi);
    k2_fused<<<dim3(256), 1024, 0, stream>>>(h, Whh, bhh, wread, wwrite,
                                             gumb, gi, out);
}

// Round 10
// 80.920 us; speedup vs baseline: 1.1006x; 1.1006x over previous
//
#include <hip/hip_runtime.h>

#define NB_BS   2048
#define NB_NINP 512
#define NB_NHID 512
#define NB_K    16
#define NB_T    8
#define NB_M    32
#define NB_C    768   // T * 3 * M
#define H_OUT_ELEMS (NB_BS * NB_NHID)   // 1048576

// ---------------------------------------------------------------------------
// Kernel 1: gi'[b][c] = sum_i x[b][i]*Wih[c][i] + bih[c] + (gate<2 ? bhh[c] : 0)
// 64x96 tile, 512 threads, K-split (kg halves of K=512), 4x6 micro-tile.
// r7's structure (best measured k1 ~25.6us, DS-model-validated) with ONE
// change: wave = 4 row-groups x 16 col-threads so the av b128 has only 4
// unique addresses per wave (broadcast ~5cyc instead of 16-addr spread
// ~12cyc). wv = 3x b64 at 16 unique banks (6*cg mod 32 distinct) = free.
// DS per wave-iter 30 -> ~23 cyc => model 19.6us. Grid (32,8)=256 = 1/CU.
// ---------------------------------------------------------------------------
__global__ __launch_bounds__(512, 2)
void k1_gemm_gi(const float* __restrict__ x, const float* __restrict__ Wih,
                const float* __restrict__ bih, const float* __restrict__ bhh,
                float* __restrict__ gi)
{
    __shared__ __align__(16) float As[2][32][68];    // [kg][k][row] 17.4 KB
    __shared__ __align__(16) float Bs[2][32][100];   // [kg][k][col] 25.6 KB
    __shared__ float ACCX[256][25];                  // 25.6 KB (25: coprime 32)

    const int tid  = threadIdx.x;
    const int kg   = tid >> 8;            // K-half: 0 -> k<256, 1 -> k>=256
    const int ttid = tid & 255;
    const int row0 = blockIdx.x * 64;
    const int col0 = blockIdx.y * 96;
    const int rg   = ttid >> 4;           // 0..15 -> rows rg*4..+3 (4/wave!)
    const int cg   = ttid & 15;           // 0..15 -> cols cg*6..+5
    const int kb0  = kg * 256;

    // A staging: 2 float4/thread (64 rows x 8 k-quads)
    const int ar0 = ttid >> 3, akq = (ttid & 7) * 4, ar1 = ar0 + 32;
    // B staging: 3 float4/thread (96 cols x 8 k-quads)
    const int c0 = ttid >> 3, c1 = c0 + 32, c2 = c0 + 64;

    float4 a0 = *(const float4*)&x[(size_t)(row0 + ar0) * NB_NINP + kb0 + akq];
    float4 a1 = *(const float4*)&x[(size_t)(row0 + ar1) * NB_NINP + kb0 + akq];
    float4 b0 = *(const float4*)&Wih[(size_t)(col0 + c0) * NB_NINP + kb0 + akq];
    float4 b1 = *(const float4*)&Wih[(size_t)(col0 + c1) * NB_NINP + kb0 + akq];
    float4 b2 = *(const float4*)&Wih[(size_t)(col0 + c2) * NB_NINP + kb0 + akq];

    float acc[4][6];
    #pragma unroll
    for (int i = 0; i < 4; ++i)
        #pragma unroll
        for (int e = 0; e < 6; ++e) acc[i][e] = 0.f;

    for (int slab = 0; slab < 8; ++slab) {
        __syncthreads();
        As[kg][akq+0][ar0]=a0.x; As[kg][akq+1][ar0]=a0.y;
        As[kg][akq+2][ar0]=a0.z; As[kg][akq+3][ar0]=a0.w;
        As[kg][akq+0][ar1]=a1.x; As[kg][akq+1][ar1]=a1.y;
        As[kg][akq+2][ar1]=a1.z; As[kg][akq+3][ar1]=a1.w;
        Bs[kg][akq+0][c0]=b0.x; Bs[kg][akq+1][c0]=b0.y;
        Bs[kg][akq+2][c0]=b0.z; Bs[kg][akq+3][c0]=b0.w;
        Bs[kg][akq+0][c1]=b1.x; Bs[kg][akq+1][c1]=b1.y;
        Bs[kg][akq+2][c1]=b1.z; Bs[kg][akq+3][c1]=b1.w;
        Bs[kg][akq+0][c2]=b2.x; Bs[kg][akq+1][c2]=b2.y;
        Bs[kg][akq+2][c2]=b2.z; Bs[kg][akq+3][c2]=b2.w;
        __syncthreads();
        if (slab < 7) {   // prefetch next slab of this K-half (overlaps compute)
            const int kb = kb0 + (slab + 1) * 32;
            a0 = *(const float4*)&x[(size_t)(row0 + ar0) * NB_NINP + kb + akq];
            a1 = *(const float4*)&x[(size_t)(row0 + ar1) * NB_NINP + kb + akq];
            b0 = *(const float4*)&Wih[(size_t)(col0 + c0) * NB_NINP + kb + akq];
            b1 = *(const float4*)&Wih[(size_t)(col0 + c1) * NB_NINP + kb + akq];
            b2 = *(const float4*)&Wih[(size_t)(col0 + c2) * NB_NINP + kb + akq];
        }
        #pragma unroll
        for (int kk = 0; kk < 32; ++kk) {
            const float4 av = *(const float4*)&As[kg][kk][rg * 4];    // 4-addr bc
            const float2 w0 = *(const float2*)&Bs[kg][kk][cg * 6];
            const float2 w1 = *(const float2*)&Bs[kg][kk][cg * 6 + 2];
            const float2 w2 = *(const float2*)&Bs[kg][kk][cg * 6 + 4];
            const float avv[4] = {av.x, av.y, av.z, av.w};
            const float wvv[6] = {w0.x, w0.y, w1.x, w1.y, w2.x, w2.y};
            #pragma unroll
            for (int i = 0; i < 4; ++i)
                #pragma unroll
                for (int e = 0; e < 6; ++e)
                    acc[i][e] = fmaf(avv[i], wvv[e], acc[i][e]);
        }
    }

    __syncthreads();
    if (kg == 1) {                        // publish K-half-1 partials
        #pragma unroll
        for (int i = 0; i < 4; ++i)
            #pragma unroll
            for (int e = 0; e < 6; ++e) ACCX[ttid][i * 6 + e] = acc[i][e];
    }
    __syncthreads();
    if (kg == 0) {                        // combine + bias + store
        float bias[6];
        #pragma unroll
        for (int e = 0; e < 6; ++e) {
            const int cl = cg * 6 + e;    // c % 96
            const int c  = col0 + cl;
            bias[e] = bih[c] + (cl < 64 ? bhh[c] : 0.f);
        }
        #pragma unroll
        for (int i = 0; i < 4; ++i) {
            const size_t base = (size_t)(row0 + rg * 4 + i) * NB_C + col0 + cg * 6;
            #pragma unroll
            for (int e = 0; e < 6; e += 2) {
                float2 o;
                o.x = acc[i][e]   + ACCX[ttid][i*6+e]   + bias[e];
                o.y = acc[i][e+1] + ACCX[ttid][i*6+e+1] + bias[e+1];
                *(float2*)&gi[base + e] = o;
            }
        }
    }
}

// ---------------------------------------------------------------------------
// Kernel 2: fused gh-GEMM + GRU + write-key logits + gumbel-argmax + gather.
// r9 structure verbatim (proven 52.9us / 60 VGPR / no spill): 256 x 1024 thr,
// wave (bl,kh), 2 passes of 4 k's, acc[4][12], packed-butterfly epilogue.
// ONE change: s_setprio(1) around the mm-loop FMA cluster (T5 -- waves
// diverge after the single barrier, so priority arbitration has room).
// ---------------------------------------------------------------------------
__global__ __launch_bounds__(1024)
__attribute__((amdgpu_waves_per_eu(4, 4)))
void k2_fused(const float* __restrict__ h,      const float* __restrict__ Whh,
              const float* __restrict__ bhh,    const float* __restrict__ wread,
              const float* __restrict__ wwrite, const float* __restrict__ gumb,
              const float* __restrict__ gi,     float* __restrict__ out)
{
    __shared__ __align__(16) float4 P[3][32][64];   // 98304 B  W_hh planes
    __shared__ __align__(16) float4 WWT4[16][64];   // 16384 B  [f][half*32+m]:p-quad
    __shared__ __align__(16) float WR[512];         //  2048 B  w_read [m][f]
    __shared__ __align__(16) float HT[8][32][20];   // 20480 B  [bl][m][k]
    __shared__ __align__(16) float HR2T[8][16][20]; // 10240 B  [bl][f][k]
    __shared__ __align__(16) float LG[8][16][8];    //  4096 B  [bl][k][t]

    const int tid  = threadIdx.x;
    const int wave = tid >> 6, lane = tid & 63;
    const int bl   = wave >> 1, kh = wave & 1;
    const int b    = blockIdx.x * 8 + bl;
    const int m_   = lane & 31, half = lane >> 5;

    // ---- stage W_hh planes (value for reading-lane sl at contraction mm
    //      lands at float4 slot sl ^ (mm&7) of row [j>>2][mm])
    float* PF = (float*)P;
    for (int i = tid; i < 24576; i += 1024) {       // Whh flat [c][m]; c=t*96+gc*32+mout
        const int c = i >> 5, mm = i & 31;
        const int t = c / 96, rem = c - t * 96;
        const int gc = rem >> 5, mout = rem & 31;
        const int j  = (t >> 1) * 3 + gc;
        const int sl = ((t & 1) * 32 + mout) ^ (mm & 7);
        PF[(((j >> 2) * 32 + mm) * 64 + sl) * 4 + (j & 3)] = Whh[i];
    }
    for (int i = tid; i < 4096; i += 1024) {        // wwrite flat [t][m][f]
        const int t = i >> 9, mo = (i >> 4) & 31, f = i & 15;
        ((float*)WWT4)[(f * 64 + (t & 1) * 32 + mo) * 4 + (t >> 1)] = wwrite[i];
    }
    if (tid < 512) WR[tid] = wread[tid];
    #pragma unroll
    for (int e = 0; e < 4; ++e) {                   // this wave's h half-row, transposed
        const int idx = kh * 256 + e * 64 + lane;
        HT[bl][idx & 31][idx >> 5] = h[(size_t)b * NB_NHID + idx];
    }
    __syncthreads();   // only barrier; everything below is wave-local

    // ---- h_read for this wave's 8 k's: lane owns (k = kh*8 + lane>>3, f-pair)
    {
        const int kq = kh * 8 + (lane >> 3);
        const int f0 = (lane & 7) * 2;
        float s0 = 0.f, s1 = 0.f;
        #pragma unroll 8
        for (int mm = 0; mm < 32; ++mm) {
            const float hv = HT[bl][mm][kq];
            s0 = fmaf(hv, WR[mm * 16 + f0], s0);
            s1 = fmaf(hv, WR[mm * 16 + f0 + 1], s1);
        }
        HR2T[bl][f0    ][kq] = s0;
        HR2T[bl][f0 + 1][kq] = s1;
    }

    // ---- per-lane gi' (bih+bhh_{r,z} folded by k1) and bhh_n
    float gi_r[4][3], bhn[4];
    #pragma unroll
    for (int p = 0; p < 4; ++p) {
        const int t = 2 * p + half;
        #pragma unroll
        for (int gc = 0; gc < 3; ++gc)
            gi_r[p][gc] = gi[(size_t)b * NB_C + t * 96 + gc * 32 + m_];
        bhn[p] = bhh[t * 96 + 64 + m_];
    }

    #pragma unroll 1
    for (int pass = 0; pass < 2; ++pass) {
        const int k0 = kh * 8 + pass * 4;

        // ---- gh GEMM, 4 k's: 48 FMA per mm; 3 spread b128 + 1 broadcast b128
        float acc[4][12];
        #pragma unroll
        for (int r = 0; r < 4; ++r)
            #pragma unroll
            for (int j = 0; j < 12; ++j) acc[r][j] = 0.f;

        __builtin_amdgcn_s_setprio(1);
        #pragma unroll 4
        for (int mm = 0; mm < 32; ++mm) {
            const int sw = lane ^ (mm & 7);          // undo staging swizzle
            const float4 w0 = P[0][mm][sw];
            const float4 w1 = P[1][mm][sw];
            const float4 w2 = P[2][mm][sw];
            const float4 hv = *(const float4*)&HT[bl][mm][k0];   // broadcast
            const float wj[12] = {w0.x,w0.y,w0.z,w0.w, w1.x,w1.y,w1.z,w1.w,
                                  w2.x,w2.y,w2.z,w2.w};
            const float hr4[4] = {hv.x, hv.y, hv.z, hv.w};
            #pragma unroll
            for (int r = 0; r < 4; ++r)
                #pragma unroll
                for (int j = 0; j < 12; ++j)
                    acc[r][j] = fmaf(hr4[r], wj[j], acc[r][j]);
        }
        __builtin_amdgcn_s_setprio(0);

        // ---- write-key dot ww[r][p] = sum_f w_write[t][m_][f] * h_read[k][f]
        float ww[4][4];
        #pragma unroll
        for (int r = 0; r < 4; ++r)
            #pragma unroll
            for (int p = 0; p < 4; ++p) ww[r][p] = 0.f;
        #pragma unroll 4
        for (int f = 0; f < 16; ++f) {
            const float4 wt4 = WWT4[f][half * 32 + m_];           // b128 spread
            const float4 hka = *(const float4*)&HR2T[bl][f][k0];  // broadcast
            const float wt[4] = {wt4.x, wt4.y, wt4.z, wt4.w};
            const float hk[4] = {hka.x, hka.y, hka.z, hka.w};
            #pragma unroll
            for (int r = 0; r < 4; ++r)
                #pragma unroll
                for (int p = 0; p < 4; ++p)
                    ww[r][p] = fmaf(hk[r], wt[p], ww[r][p]);
        }

        // ---- per-k epilogue: gates, packed logit reduce, argmax, gather
        #pragma unroll
        for (int r = 0; r < 4; ++r) {
            const int k = k0 + r;
            const float h2v = HT[bl][m_][k];
            float hn[4], part[4];
            #pragma unroll
            for (int p = 0; p < 4; ++p) {
                const float xr = gi_r[p][0] + acc[r][p*3+0];
                const float xz = gi_r[p][1] + acc[r][p*3+1];
                const float gn = bhn[p]     + acc[r][p*3+2];
                const float rg = 1.f / (1.f + __expf(-xr));
                const float zg = 1.f / (1.f + __expf(-xz));
                const float xn = gi_r[p][2] + rg * gn;
                const float e2 = __expf(2.f * xn);
                const float tn = 1.f - 2.f / (e2 + 1.f);   // tanh
                const float hv2 = (1.f - zg) * tn + zg * h2v;
                hn[p] = hv2;
                part[p] = hv2 * ww[r][p];                  // logit partial
            }
            // packed butterfly over m: p-low -> lane bit4, p-high -> lane bit3
            #pragma unroll
            for (int p = 0; p < 4; ++p)
                part[p] += __shfl_xor(part[p], 16, 64);
            const bool b4 = (lane & 16) != 0, b3 = (lane & 8) != 0;
            float v01 = b4 ? part[1] : part[0];
            float v23 = b4 ? part[3] : part[2];
            v01 += __shfl_xor(v01, 8, 64);
            v23 += __shfl_xor(v23, 8, 64);
            float v = b3 ? v23 : v01;
            v += __shfl_xor(v, 4, 64);
            v += __shfl_xor(v, 2, 64);
            v += __shfl_xor(v, 1, 64);
            if ((lane & 7) == 0) {       // 8 lanes: one per (p,half) = t
                const int p_ = ((lane >> 4) & 1) | (((lane >> 3) & 1) << 1);
                LG[bl][k][2 * p_ + half] = v;
            }
            // same-wave DS ordering: LG[k][0..7] complete for this wave's k
            const float4 l0 = *(const float4*)&LG[bl][k][0];   // broadcast
            const float4 l1 = *(const float4*)&LG[bl][k][4];
            const float* gp = gumb + ((size_t)b * NB_K + k) * NB_T;
            const float4 ga = *(const float4*)gp;
            const float4 gb = *(const float4*)(gp + 4);
            const float s[8] = {l0.x+ga.x, l0.y+ga.y, l0.z+ga.z, l0.w+ga.w,
                                l1.x+gb.x, l1.y+gb.y, l1.z+gb.z, l1.w+gb.w};
            float best = s[0]; int bt = 0;
            #pragma unroll
            for (int t2 = 1; t2 < 8; ++t2)
                if (s[t2] > best) { best = s[t2]; bt = t2; }   // first-max
            const int pstar = bt >> 1, hstar = bt & 1;
            float hsel = hn[0];
            hsel = (pstar == 1) ? hn[1] : hsel;
            hsel = (pstar == 2) ? hn[2] : hsel;
            hsel = (pstar == 3) ? hn[3] : hsel;
            if (half == hstar)
                out[(size_t)b * NB_NHID + k * 32 + m_] = hsel;
            if (lane < 8)
                out[H_OUT_ELEMS + ((size_t)b * NB_K + k) * NB_T + lane] =
                    (lane == bt) ? 1.f : 0.f;
        }
    }
}

extern "C" void kernel_launch(void* const* d_in, const int* in_sizes, int n_in,
                              void* d_out, int out_size, void* d_ws, size_t ws_size,
                              hipStream_t stream) {
    const float* x      = (const float*)d_in[0];
    const float* h      = (const float*)d_in[1];
    const float* Wih    = (const float*)d_in[2];
    const float* Whh    = (const float*)d_in[3];
    const float* bih    = (const float*)d_in[4];
    const float* bhh    = (const float*)d_in[5];
    const float* wread  = (const float*)d_in[6];
    const float* wwrite = (const float*)d_in[7];
    const float* gumb   = (const float*)d_in[8];
    float* out = (float*)d_out;
    float* gi  = (float*)d_ws;   // 2048*768*4 = 6 MB scratch

    k1_gemm_gi<<<dim3(32, 8), 512, 0, stream>>>(x, Wih, bih, bhh, gi);
    k2_fused<<<dim3(256), 1024, 0, stream>>>(h, Whh, bhh, wread, wwrite,
                                             gumb, gi, out);
}

// Round 11
// 78.996 us; speedup vs baseline: 1.1274x; 1.0244x over previous
//
#include <hip/hip_runtime.h>

#define NB_BS   2048
#define NB_NINP 512
#define NB_NHID 512
#define NB_K    16
#define NB_T    8
#define NB_M    32
#define NB_C    768   // T * 3 * M
#define H_OUT_ELEMS (NB_BS * NB_NHID)   // 1048576

// ---------------------------------------------------------------------------
// Kernel 1: gi'[b][c] = sum_i x[b][i]*Wih[c][i] + bih[c] + (gate<2 ? bhh[c] : 0)
// 64x96 tile, 1024 threads, K-SPLIT-4: kg = tid>>8 owns K-quarter kg*128..+127
// with 256 threads at the proven 4x6 micro (av = 4-addr broadcast b128,
// wv = 3 conflict-free b64 at 16 unique bank-pairs). Grid (32,8) = 256 =
// 1 block/CU balanced -> 16 waves/CU = 4 waves/SIMD (r10 ran 2 and sat at
// ~29us vs a 15.3us CU-DS floor). BK=16 slabs keep stage regs ~12 so total
// reg demand ~55 stays under the 64-VGPR wall of 1024-thr blocks (r6/r8
// lesson). Partials combine through one reused ACCX buffer, 3 rounds.
// ---------------------------------------------------------------------------
__global__ __launch_bounds__(1024)
void k1_gemm_gi(const float* __restrict__ x, const float* __restrict__ Wih,
                const float* __restrict__ bih, const float* __restrict__ bhh,
                float* __restrict__ gi)
{
    __shared__ __align__(16) float As[4][16][68];    // [kg][k][row] 17.4 KB
    __shared__ __align__(16) float Bs[4][16][100];   // [kg][k][col] 25.6 KB
    __shared__ float ACCX[256][25];                  // 25.6 KB (25 coprime 32)

    const int tid  = threadIdx.x;
    const int kg   = tid >> 8;            // K-quarter
    const int ttid = tid & 255;
    const int row0 = blockIdx.x * 64;
    const int col0 = blockIdx.y * 96;
    const int rg   = ttid >> 4;           // 0..15 -> rows rg*4..+3 (4/wave)
    const int cg   = ttid & 15;           // 0..15 -> cols cg*6..+5
    const int kb0  = kg * 128;

    // A staging: 1 float4/thread (64 rows x 4 k-quads)
    const int ar = ttid >> 2, akq = (ttid & 3) * 4;
    // B staging: 1 float4/thread + half round (96 cols x 4 k-quads = 384 f4)
    const int bc0 = ttid >> 2,              bk0 = (ttid & 3) * 4;
    const int bc1 = (256 + ttid) >> 2,      bk1 = (ttid & 3) * 4;  // ttid<128

    float4 a0 = *(const float4*)&x[(size_t)(row0 + ar) * NB_NINP + kb0 + akq];
    float4 b0 = *(const float4*)&Wih[(size_t)(col0 + bc0) * NB_NINP + kb0 + bk0];
    float4 b1;
    if (ttid < 128)
        b1 = *(const float4*)&Wih[(size_t)(col0 + bc1) * NB_NINP + kb0 + bk1];

    float acc[4][6];
    #pragma unroll
    for (int i = 0; i < 4; ++i)
        #pragma unroll
        for (int e = 0; e < 6; ++e) acc[i][e] = 0.f;

    for (int slab = 0; slab < 8; ++slab) {           // 8 slabs of BK=16
        __syncthreads();
        As[kg][akq+0][ar]=a0.x; As[kg][akq+1][ar]=a0.y;
        As[kg][akq+2][ar]=a0.z; As[kg][akq+3][ar]=a0.w;
        Bs[kg][bk0+0][bc0]=b0.x; Bs[kg][bk0+1][bc0]=b0.y;
        Bs[kg][bk0+2][bc0]=b0.z; Bs[kg][bk0+3][bc0]=b0.w;
        if (ttid < 128) {
            Bs[kg][bk1+0][bc1]=b1.x; Bs[kg][bk1+1][bc1]=b1.y;
            Bs[kg][bk1+2][bc1]=b1.z; Bs[kg][bk1+3][bc1]=b1.w;
        }
        __syncthreads();
        if (slab < 7) {   // prefetch next slab of this K-quarter
            const int kb = kb0 + (slab + 1) * 16;
            a0 = *(const float4*)&x[(size_t)(row0 + ar) * NB_NINP + kb + akq];
            b0 = *(const float4*)&Wih[(size_t)(col0 + bc0) * NB_NINP + kb + bk0];
            if (ttid < 128)
                b1 = *(const float4*)&Wih[(size_t)(col0 + bc1) * NB_NINP + kb + bk1];
        }
        #pragma unroll
        for (int kk = 0; kk < 16; ++kk) {
            const float4 av = *(const float4*)&As[kg][kk][rg * 4];   // 4-addr bc
            const float2 w0 = *(const float2*)&Bs[kg][kk][cg * 6];
            const float2 w1 = *(const float2*)&Bs[kg][kk][cg * 6 + 2];
            const float2 w2 = *(const float2*)&Bs[kg][kk][cg * 6 + 4];
            const float avv[4] = {av.x, av.y, av.z, av.w};
            const float wvv[6] = {w0.x, w0.y, w1.x, w1.y, w2.x, w2.y};
            #pragma unroll
            for (int i = 0; i < 4; ++i)
                #pragma unroll
                for (int e = 0; e < 6; ++e)
                    acc[i][e] = fmaf(avv[i], wvv[e], acc[i][e]);
        }
    }

    // ---- combine the 4 K-quarter partials through one reused buffer
    #pragma unroll 1
    for (int src = 1; src < 4; ++src) {
        __syncthreads();
        if (kg == src) {
            #pragma unroll
            for (int i = 0; i < 4; ++i)
                #pragma unroll
                for (int e = 0; e < 6; ++e) ACCX[ttid][i * 6 + e] = acc[i][e];
        }
        __syncthreads();
        if (kg == 0) {
            #pragma unroll
            for (int i = 0; i < 4; ++i)
                #pragma unroll
                for (int e = 0; e < 6; ++e) acc[i][e] += ACCX[ttid][i * 6 + e];
        }
    }
    if (kg == 0) {                        // bias + store
        float bias[6];
        #pragma unroll
        for (int e = 0; e < 6; ++e) {
            const int cl = cg * 6 + e;    // c % 96
            const int c  = col0 + cl;
            bias[e] = bih[c] + (cl < 64 ? bhh[c] : 0.f);
        }
        #pragma unroll
        for (int i = 0; i < 4; ++i) {
            const size_t base = (size_t)(row0 + rg * 4 + i) * NB_C + col0 + cg * 6;
            #pragma unroll
            for (int e = 0; e < 6; e += 2) {
                float2 o;
                o.x = acc[i][e]   + bias[e];
                o.y = acc[i][e+1] + bias[e+1];
                *(float2*)&gi[base + e] = o;
            }
        }
    }
}

// ---------------------------------------------------------------------------
// Kernel 2: fused gh-GEMM + GRU + write-key logits + gumbel-argmax + gather.
// r10 verbatim (best measured: 50.2us / 60 VGPR / no spill): 256 x 1024 thr,
// wave (bl,kh), 2 passes of 4 k's, acc[4][12], setprio around the FMA
// cluster, packed-butterfly logit reduce + wave-local LG exchange.
// ---------------------------------------------------------------------------
__global__ __launch_bounds__(1024)
__attribute__((amdgpu_waves_per_eu(4, 4)))
void k2_fused(const float* __restrict__ h,      const float* __restrict__ Whh,
              const float* __restrict__ bhh,    const float* __restrict__ wread,
              const float* __restrict__ wwrite, const float* __restrict__ gumb,
              const float* __restrict__ gi,     float* __restrict__ out)
{
    __shared__ __align__(16) float4 P[3][32][64];   // 98304 B  W_hh planes
    __shared__ __align__(16) float4 WWT4[16][64];   // 16384 B  [f][half*32+m]:p-quad
    __shared__ __align__(16) float WR[512];         //  2048 B  w_read [m][f]
    __shared__ __align__(16) float HT[8][32][20];   // 20480 B  [bl][m][k]
    __shared__ __align__(16) float HR2T[8][16][20]; // 10240 B  [bl][f][k]
    __shared__ __align__(16) float LG[8][16][8];    //  4096 B  [bl][k][t]

    const int tid  = threadIdx.x;
    const int wave = tid >> 6, lane = tid & 63;
    const int bl   = wave >> 1, kh = wave & 1;
    const int b    = blockIdx.x * 8 + bl;
    const int m_   = lane & 31, half = lane >> 5;

    // ---- stage W_hh planes (value for reading-lane sl at contraction mm
    //      lands at float4 slot sl ^ (mm&7) of row [j>>2][mm])
    float* PF = (float*)P;
    for (int i = tid; i < 24576; i += 1024) {       // Whh flat [c][m]; c=t*96+gc*32+mout
        const int c = i >> 5, mm = i & 31;
        const int t = c / 96, rem = c - t * 96;
        const int gc = rem >> 5, mout = rem & 31;
        const int j  = (t >> 1) * 3 + gc;
        const int sl = ((t & 1) * 32 + mout) ^ (mm & 7);
        PF[(((j >> 2) * 32 + mm) * 64 + sl) * 4 + (j & 3)] = Whh[i];
    }
    for (int i = tid; i < 4096; i += 1024) {        // wwrite flat [t][m][f]
        const int t = i >> 9, mo = (i >> 4) & 31, f = i & 15;
        ((float*)WWT4)[(f * 64 + (t & 1) * 32 + mo) * 4 + (t >> 1)] = wwrite[i];
    }
    if (tid < 512) WR[tid] = wread[tid];
    #pragma unroll
    for (int e = 0; e < 4; ++e) {                   // this wave's h half-row, transposed
        const int idx = kh * 256 + e * 64 + lane;
        HT[bl][idx & 31][idx >> 5] = h[(size_t)b * NB_NHID + idx];
    }
    __syncthreads();   // only barrier; everything below is wave-local

    // ---- h_read for this wave's 8 k's: lane owns (k = kh*8 + lane>>3, f-pair)
    {
        const int kq = kh * 8 + (lane >> 3);
        const int f0 = (lane & 7) * 2;
        float s0 = 0.f, s1 = 0.f;
        #pragma unroll 8
        for (int mm = 0; mm < 32; ++mm) {
            const float hv = HT[bl][mm][kq];
            s0 = fmaf(hv, WR[mm * 16 + f0], s0);
            s1 = fmaf(hv, WR[mm * 16 + f0 + 1], s1);
        }
        HR2T[bl][f0    ][kq] = s0;
        HR2T[bl][f0 + 1][kq] = s1;
    }

    // ---- per-lane gi' (bih+bhh_{r,z} folded by k1) and bhh_n
    float gi_r[4][3], bhn[4];
    #pragma unroll
    for (int p = 0; p < 4; ++p) {
        const int t = 2 * p + half;
        #pragma unroll
        for (int gc = 0; gc < 3; ++gc)
            gi_r[p][gc] = gi[(size_t)b * NB_C + t * 96 + gc * 32 + m_];
        bhn[p] = bhh[t * 96 + 64 + m_];
    }

    #pragma unroll 1
    for (int pass = 0; pass < 2; ++pass) {
        const int k0 = kh * 8 + pass * 4;

        // ---- gh GEMM, 4 k's: 48 FMA per mm; 3 spread b128 + 1 broadcast b128
        float acc[4][12];
        #pragma unroll
        for (int r = 0; r < 4; ++r)
            #pragma unroll
            for (int j = 0; j < 12; ++j) acc[r][j] = 0.f;

        __builtin_amdgcn_s_setprio(1);
        #pragma unroll 4
        for (int mm = 0; mm < 32; ++mm) {
            const int sw = lane ^ (mm & 7);          // undo staging swizzle
            const float4 w0 = P[0][mm][sw];
            const float4 w1 = P[1][mm][sw];
            const float4 w2 = P[2][mm][sw];
            const float4 hv = *(const float4*)&HT[bl][mm][k0];   // broadcast
            const float wj[12] = {w0.x,w0.y,w0.z,w0.w, w1.x,w1.y,w1.z,w1.w,
                                  w2.x,w2.y,w2.z,w2.w};
            const float hr4[4] = {hv.x, hv.y, hv.z, hv.w};
            #pragma unroll
            for (int r = 0; r < 4; ++r)
                #pragma unroll
                for (int j = 0; j < 12; ++j)
                    acc[r][j] = fmaf(hr4[r], wj[j], acc[r][j]);
        }
        __builtin_amdgcn_s_setprio(0);

        // ---- write-key dot ww[r][p] = sum_f w_write[t][m_][f] * h_read[k][f]
        float ww[4][4];
        #pragma unroll
        for (int r = 0; r < 4; ++r)
            #pragma unroll
            for (int p = 0; p < 4; ++p) ww[r][p] = 0.f;
        #pragma unroll 4
        for (int f = 0; f < 16; ++f) {
            const float4 wt4 = WWT4[f][half * 32 + m_];           // b128 spread
            const float4 hka = *(const float4*)&HR2T[bl][f][k0];  // broadcast
            const float wt[4] = {wt4.x, wt4.y, wt4.z, wt4.w};
            const float hk[4] = {hka.x, hka.y, hka.z, hka.w};
            #pragma unroll
            for (int r = 0; r < 4; ++r)
                #pragma unroll
                for (int p = 0; p < 4; ++p)
                    ww[r][p] = fmaf(hk[r], wt[p], ww[r][p]);
        }

        // ---- per-k epilogue: gates, packed logit reduce, argmax, gather
        #pragma unroll
        for (int r = 0; r < 4; ++r) {
            const int k = k0 + r;
            const float h2v = HT[bl][m_][k];
            float hn[4], part[4];
            #pragma unroll
            for (int p = 0; p < 4; ++p) {
                const float xr = gi_r[p][0] + acc[r][p*3+0];
                const float xz = gi_r[p][1] + acc[r][p*3+1];
                const float gn = bhn[p]     + acc[r][p*3+2];
                const float rg = 1.f / (1.f + __expf(-xr));
                const float zg = 1.f / (1.f + __expf(-xz));
                const float xn = gi_r[p][2] + rg * gn;
                const float e2 = __expf(2.f * xn);
                const float tn = 1.f - 2.f / (e2 + 1.f);   // tanh
                const float hv2 = (1.f - zg) * tn + zg * h2v;
                hn[p] = hv2;
                part[p] = hv2 * ww[r][p];                  // logit partial
            }
            // packed butterfly over m: p-low -> lane bit4, p-high -> lane bit3
            #pragma unroll
            for (int p = 0; p < 4; ++p)
                part[p] += __shfl_xor(part[p], 16, 64);
            const bool b4 = (lane & 16) != 0, b3 = (lane & 8) != 0;
            float v01 = b4 ? part[1] : part[0];
            float v23 = b4 ? part[3] : part[2];
            v01 += __shfl_xor(v01, 8, 64);
            v23 += __shfl_xor(v23, 8, 64);
            float v = b3 ? v23 : v01;
            v += __shfl_xor(v, 4, 64);
            v += __shfl_xor(v, 2, 64);
            v += __shfl_xor(v, 1, 64);
            if ((lane & 7) == 0) {       // 8 lanes: one per (p,half) = t
                const int p_ = ((lane >> 4) & 1) | (((lane >> 3) & 1) << 1);
                LG[bl][k][2 * p_ + half] = v;
            }
            // same-wave DS ordering: LG[k][0..7] complete for this wave's k
            const float4 l0 = *(const float4*)&LG[bl][k][0];   // broadcast
            const float4 l1 = *(const float4*)&LG[bl][k][4];
            const float* gp = gumb + ((size_t)b * NB_K + k) * NB_T;
            const float4 ga = *(const float4*)gp;
            const float4 gb = *(const float4*)(gp + 4);
            const float s[8] = {l0.x+ga.x, l0.y+ga.y, l0.z+ga.z, l0.w+ga.w,
                                l1.x+gb.x, l1.y+gb.y, l1.z+gb.z, l1.w+gb.w};
            float best = s[0]; int bt = 0;
            #pragma unroll
            for (int t2 = 1; t2 < 8; ++t2)
                if (s[t2] > best) { best = s[t2]; bt = t2; }   // first-max
            const int pstar = bt >> 1, hstar = bt & 1;
            float hsel = hn[0];
            hsel = (pstar == 1) ? hn[1] : hsel;
            hsel = (pstar == 2) ? hn[2] : hsel;
            hsel = (pstar == 3) ? hn[3] : hsel;
            if (half == hstar)
                out[(size_t)b * NB_NHID + k * 32 + m_] = hsel;
            if (lane < 8)
                out[H_OUT_ELEMS + ((size_t)b * NB_K + k) * NB_T + lane] =
                    (lane == bt) ? 1.f : 0.f;
        }
    }
}

extern "C" void kernel_launch(void* const* d_in, const int* in_sizes, int n_in,
                              void* d_out, int out_size, void* d_ws, size_t ws_size,
                              hipStream_t stream) {
    const float* x      = (const float*)d_in[0];
    const float* h      = (const float*)d_in[1];
    const float* Wih    = (const float*)d_in[2];
    const float* Whh    = (const float*)d_in[3];
    const float* bih    = (const float*)d_in[4];
    const float* bhh    = (const float*)d_in[5];
    const float* wread  = (const float*)d_in[6];
    const float* wwrite = (const float*)d_in[7];
    const float* gumb   = (const float*)d_in[8];
    float* out = (float*)d_out;
    float* gi  = (float*)d_ws;   // 2048*768*4 = 6 MB scratch

    k1_gemm_gi<<<dim3(32, 8), 1024, 0, stream>>>(x, Wih, bih, bhh, gi);
    k2_fused<<<dim3(256), 1024, 0, stream>>>(h, Whh, bhh, wread, wwrite,
                                             gumb, gi, out);
}